// Round 14
// baseline (1676.148 us; speedup 1.0000x reference)
//
#include <hip/hip_runtime.h>

#define MDIM 1024
#define H4   4096
#define TKL  10
#define NT   30
#define NWFR 39
#define GBLK 512
#define GTHR 1024
#define AGENT __HIP_MEMORY_SCOPE_AGENT

typedef _Float16 h2v __attribute__((ext_vector_type(2)));
typedef unsigned int uv4 __attribute__((ext_vector_type(4)));
typedef unsigned int uv2 __attribute__((ext_vector_type(2)));
typedef float fv4 __attribute__((ext_vector_type(4)));
union U16 { uv4 u; h2v h[4]; _Float16 f[8]; };

__device__ __forceinline__ float wred(float v) {
#pragma unroll
  for (int o = 32; o; o >>= 1) v += __shfl_xor(v, o, 64);
  return v;
}

__device__ __forceinline__ float dot16(const U16& w, const U16& x, float acc) {
  acc = __builtin_amdgcn_fdot2(w.h[0], x.h[0], acc, false);
  acc = __builtin_amdgcn_fdot2(w.h[1], x.h[1], acc, false);
  acc = __builtin_amdgcn_fdot2(w.h[2], x.h[2], acc, false);
  acc = __builtin_amdgcn_fdot2(w.h[3], x.h[3], acc, false);
  return acc;
}

// write-through stores (visible at coherence point, never dirty in L2)
__device__ __forceinline__ void stg16(const void* p, uv4 v) {
  asm volatile("global_store_dwordx4 %0, %1, off sc0 sc1" :: "v"(p), "v"(v) : "memory");
}
__device__ __forceinline__ void stg8(const void* p, uv2 v) {
  asm volatile("global_store_dwordx2 %0, %1, off sc0 sc1" :: "v"(p), "v"(v) : "memory");
}

__global__ void k_cvt(const float* __restrict__ in, _Float16* __restrict__ out, int n8) {
  int g = blockIdx.x * blockDim.x + threadIdx.x;
  if (g >= n8) return;
  const float4* p = (const float4*)in;
  float4 a = p[2 * g], b = p[2 * g + 1];
  U16 o;
  o.f[0] = (_Float16)a.x; o.f[1] = (_Float16)a.y;
  o.f[2] = (_Float16)a.z; o.f[3] = (_Float16)a.w;
  o.f[4] = (_Float16)b.x; o.f[5] = (_Float16)b.y;
  o.f[6] = (_Float16)b.z; o.f[7] = (_Float16)b.w;
  ((uv4*)out)[g] = o.u;
}

__global__ void k_xcf(const float* __restrict__ x, float* __restrict__ xcf) {
  int idx = blockIdx.x * blockDim.x + threadIdx.x;
  if (idx >= NT * MDIM) return;
  int i = idx >> 10, m = idx & (MDIM - 1);
  int c = m & 31, s = m >> 5;
  const float* p = x + c * (32 * 360) + s * 360 + i * 12;
  float acc = 0.f;
#pragma unroll
  for (int k = 0; k < 12; ++k) acc += p[k];
  xcf[idx] = acc * (1.0f / 12.0f);
}

__global__ void k_s0(const float* __restrict__ xcf, const float* __restrict__ W,
                     float* __restrict__ S, float* __restrict__ Smir) {
  int wid = (blockIdx.x * blockDim.x + threadIdx.x) >> 6;
  int lane = threadIdx.x & 63;
  if (wid >= NT * MDIM) return;
  int i = wid >> 10, m = wid & (MDIM - 1);
  const float4* wr = (const float4*)(W + (size_t)m * MDIM);
  const float4* xr = (const float4*)(xcf + i * MDIM);
  float acc = 0.f;
#pragma unroll
  for (int k = 0; k < 4; ++k) {
    float4 w = wr[lane + (k << 6)];
    float4 xv = xr[lane + (k << 6)];
    acc += w.x * xv.x + w.y * xv.y + w.z * xv.z + w.w * xv.w;
  }
  acc = wred(acc);
  if (lane == 0) {
    int e = m & ~1;
    float ang = (float)i / powf(10000.0f, (float)e / 512.0f);
    float pe = (m & 1) ? cosf(ang) : sinf(ang);
    float val = acc + pe;
    S[wid] = val;
    Smir[((size_t)i * NT + i) * MDIM + m] = val;
  }
}

// two-level fence-free barrier: 8 leaves x 64 blocks + root + go flag
__device__ __forceinline__ void gbar(unsigned* bar, unsigned ep) {
  asm volatile("s_waitcnt vmcnt(0)" ::: "memory");
  __syncthreads();
  if (threadIdx.x == 0) {
    unsigned* leaf = bar + ((blockIdx.x & 7) << 5);
    const unsigned prev = __hip_atomic_fetch_add(leaf, 1u, __ATOMIC_RELAXED, AGENT);
    if (prev == ep * 64u - 1u) {
      const unsigned r = __hip_atomic_fetch_add(bar + 256, 1u, __ATOMIC_RELAXED, AGENT);
      if (r == ep * 8u - 1u)
        __hip_atomic_store(bar + 288, ep, __ATOMIC_RELAXED, AGENT);
    }
    while (__hip_atomic_load(bar + 288, __ATOMIC_RELAXED, AGENT) < ep)
      __builtin_amdgcn_s_sleep(2);
  }
  __syncthreads();
}

// 512 blocks, 2/CU. 4-row subgroups: s = b + 512r, r<5 -> 5/block. Wo+fc1 in
// LDS; Wv non-temporal-streamed (no L2 pollution); fc2 L2-resident stream.
__global__ __launch_bounds__(GTHR, 8) void k_main(
    const _Float16* __restrict__ Wvh, const _Float16* __restrict__ Woh,
    const _Float16* __restrict__ fc1h, const float* __restrict__ fc1b,
    const _Float16* __restrict__ fc2h, const float* __restrict__ fc2b,
    const float* __restrict__ lng, const float* __restrict__ lnb,
    const float* __restrict__ lzg, const float* __restrict__ lzb,
    float* __restrict__ S, float* __restrict__ ocum,
    float* __restrict__ Smir, float* __restrict__ Omir, float* __restrict__ vmir,
    _Float16* __restrict__ hmir, unsigned* __restrict__ bar) {
  __shared__ __align__(16) _Float16 WoL[20 * MDIM];   // 40KB
  __shared__ __align__(16) _Float16 fc1L[8 * MDIM];   // 16KB
  __shared__ __align__(16) _Float16 x2L[5 * MDIM];    // 10KB
  __shared__ __align__(16) _Float16 zvL[5 * MDIM];    // 10KB: z (A) / v (B)
  __shared__ __align__(16) float4 stats[TKL];
  __shared__ __align__(16) float vOut[20];
  __shared__ __align__(16) _Float16 hgel[TKL][8];
  __shared__ float part[2][8][TKL];
  __shared__ float sOut[TKL][2];

  const int tid = threadIdx.x;
  const int lane = tid & 63;
  const int bwave = tid >> 6;
  const int b = blockIdx.x;
  unsigned ep = 0;

  __builtin_amdgcn_fence(__ATOMIC_ACQUIRE, "agent");

  int aR[5], rb[5];
#pragma unroll
  for (int r = 0; r < 5; ++r) {
    const int s = b + (r << 9);
    aR[r] = s >> 8;
    rb[r] = (s & 255) << 2;
  }

  // prologue: fc1 rows + Wo 20 rows into LDS
  ((uv4*)fc1L)[tid] = ((const uv4*)(fc1h + (size_t)b * 8192))[tid];
#pragma unroll
  for (int it = 0; it < 3; ++it) {
    const int idx = tid + (it << 10);
    if (idx < 2560) {
      const int r = idx >> 9, off = idx & 511;
      ((uv4*)WoL)[(r << 9) + off] =
          *(const uv4*)(Woh + ((size_t)aR[r] << 20) + ((size_t)rb[r] << 10) + (off << 3));
    }
  }
  __syncthreads();

  for (int t = 0; t < NWFR; ++t) {
    const int alo = (t - (NT - 1)) > 0 ? (t - (NT - 1)) : 0;
    const int ahi = t < (TKL - 1) ? t : (TKL - 1);
    const int nc = ahi - alo + 1;
    const float* Smirt = Smir + (size_t)t * NT * MDIM;
    const float* Omirt = Omir + (size_t)t * TKL * MDIM;
    bool actR[5];
#pragma unroll
    for (int r = 0; r < 5; ++r)
      actR[r] = aR[r] >= alo && aR[r] <= ahi && (t - aR[r]) != NT - 1;

    // ---- issue ALL Wv nt-loads up front (weights independent of LN/z):
    // wave w holds row-slot w; waves 0..3 additionally slot 16+w.
    U16 wvA[2], wvB[2];
    bool ldA = false, ldB = false;
    {
      const int r = bwave >> 2;
      if (actR[r]) {
        const _Float16* wp =
            Wvh + ((size_t)aR[r] << 20) + ((size_t)(rb[r] + (bwave & 3)) << 10);
        wvA[0].u = __builtin_nontemporal_load((const uv4*)wp + lane);
        wvA[1].u = __builtin_nontemporal_load((const uv4*)(wp + 512) + lane);
        ldA = true;
      }
    }
    if (bwave < 4 && actR[4]) {
      const _Float16* wp =
          Wvh + ((size_t)aR[4] << 20) + ((size_t)(rb[4] + (bwave & 3)) << 10);
      wvB[0].u = __builtin_nontemporal_load((const uv4*)wp + lane);
      wvB[1].u = __builtin_nontemporal_load((const uv4*)(wp + 512) + lane);
      ldB = true;
    }

    // ---- LN stats: one wave per cell ----
    if (bwave < nc) {
      const int a = alo + bwave, i = t - a;
      const fv4* sp = (const fv4*)(Smirt + (size_t)i * MDIM + (lane << 4));
      const fv4* op = (const fv4*)(Omirt + (size_t)a * MDIM + (lane << 4));
      fv4 sv[4], tv[4];
#pragma unroll
      for (int k = 0; k < 4; ++k) { sv[k] = sp[k]; tv[k] = sv[k] + op[k]; }
      float s1 = 0.f, t1 = 0.f;
#pragma unroll
      for (int k = 0; k < 4; ++k)
#pragma unroll
        for (int e = 0; e < 4; ++e) { s1 += sv[k][e]; t1 += tv[k][e]; }
      const float mu_s = wred(s1) * (1.0f / MDIM);
      const float mu_t = wred(t1) * (1.0f / MDIM);
      float s2 = 0.f, t2 = 0.f;
#pragma unroll
      for (int k = 0; k < 4; ++k)
#pragma unroll
        for (int e = 0; e < 4; ++e) {
          float d = sv[k][e] - mu_s; s2 += d * d;
          float f = tv[k][e] - mu_t; t2 += f * f;
        }
      const float var_s = wred(s2) * (1.0f / MDIM);
      const float var_t = wred(t2) * (1.0f / MDIM);
      if (!lane)
        stats[bwave] = make_float4(mu_s, rsqrtf(var_s + 1e-5f),
                                   mu_t, rsqrtf(var_t + 1e-5f));
    }
    __syncthreads();

    // ---- elementwise + fc1 in 2 chunks of 5 cells ----
#pragma unroll
    for (int ch = 0; ch < 2; ++ch) {
      const int c0 = ch * 5;
      if (c0 < nc) {
        {
          const int cp = tid >> 7, e = (tid & 127) << 3;
          const int c = c0 + cp;
          if (cp < 5 && c < nc) {
            const int a = alo + c, i = t - a;
            const float4 st4 = stats[c];
            fv4 sA = *(const fv4*)(Smirt + (size_t)i * MDIM + e);
            fv4 sB = *(const fv4*)(Smirt + (size_t)i * MDIM + e + 4);
            fv4 oA = *(const fv4*)(Omirt + (size_t)a * MDIM + e);
            fv4 oB = *(const fv4*)(Omirt + (size_t)a * MDIM + e + 4);
            fv4 g1A = *(const fv4*)(lng + e), g1B = *(const fv4*)(lng + e + 4);
            fv4 b1A = *(const fv4*)(lnb + e), b1B = *(const fv4*)(lnb + e + 4);
            fv4 g2A = *(const fv4*)(lzg + e), g2B = *(const fv4*)(lzg + e + 4);
            fv4 b2A = *(const fv4*)(lzb + e), b2B = *(const fv4*)(lzb + e + 4);
            U16 zz, xx;
#pragma unroll
            for (int k = 0; k < 4; ++k) {
              zz.f[k] = (_Float16)((sA[k] - st4.x) * st4.y * g1A[k] + b1A[k]);
              zz.f[4 + k] = (_Float16)((sB[k] - st4.x) * st4.y * g1B[k] + b1B[k]);
              const float u0 = sA[k] + oA[k], u1 = sB[k] + oB[k];
              xx.f[k] = (_Float16)((u0 - st4.z) * st4.w * g2A[k] + b2A[k] + u0);
              xx.f[4 + k] = (_Float16)((u1 - st4.z) * st4.w * g2B[k] + b2B[k] + u1);
            }
            *(uv4*)(x2L + cp * MDIM + e) = xx.u;
#pragma unroll
            for (int r = 0; r < 5; ++r)
              if (actR[r] && aR[r] - alo == c) *(uv4*)(zvL + r * MDIM + e) = zz.u;
          }
        }
        __syncthreads();
        if (bwave < 8) {  // fc1 row rw on this chunk's cells
          const int rw = bwave;
          U16 f0, f1;
          f0.u = *(const uv4*)(fc1L + rw * MDIM + (lane << 3));
          f1.u = *(const uv4*)(fc1L + rw * MDIM + 512 + (lane << 3));
          float sel = 0.f;
#pragma unroll
          for (int cc = 0; cc < 5; ++cc) {
            const int c = c0 + cc;
            if (c < nc) {
              U16 x0, x1;
              x0.u = *(const uv4*)(x2L + cc * MDIM + (lane << 3));
              x1.u = *(const uv4*)(x2L + cc * MDIM + 512 + (lane << 3));
              float acc = dot16(f0, x0, 0.f);
              acc = dot16(f1, x1, acc);
              acc = wred(acc);
              sel = (lane == cc) ? acc : sel;
            }
          }
          const float xg = sel + fc1b[(b << 3) | rw];
          const float ge = 0.5f * xg * (1.0f + erff(xg * 0.70710678118654752f));
          if (lane < 5 && c0 + lane < nc) hgel[c0 + lane][rw] = (_Float16)ge;
        }
        __syncthreads();
      }
    }

    // ---- Wv dots: all z ready; loads have been in flight across LN+fc1 ----
    if (ldA) {
      const int r = bwave >> 2;
      U16 z0, z1;
      z0.u = *(const uv4*)(zvL + r * MDIM + (lane << 3));
      z1.u = *(const uv4*)(zvL + r * MDIM + 512 + (lane << 3));
      float acc = dot16(wvA[0], z0, 0.f);
      acc = dot16(wvA[1], z1, acc);
      acc = wred(acc);
      if (!lane) vOut[bwave] = acc;
    }
    if (ldB) {
      U16 z0, z1;
      z0.u = *(const uv4*)(zvL + 4 * MDIM + (lane << 3));
      z1.u = *(const uv4*)(zvL + 4 * MDIM + 512 + (lane << 3));
      float acc = dot16(wvB[0], z0, 0.f);
      acc = dot16(wvB[1], z1, acc);
      acc = wred(acc);
      if (!lane) vOut[16 + bwave] = acc;
    }
    __syncthreads();
    // mirror stores: v (16B per subgroup), h (16B per cell)
    if (tid < 5 && actR[tid])
      stg16(vmir + ((size_t)t * TKL + aR[tid]) * MDIM + rb[tid],
            __builtin_bit_cast(uv4, *(const fv4*)&vOut[tid << 2]));
    if (tid < nc)
      stg16(hmir + ((size_t)t * TKL + alo + tid) * H4 + (b << 3),
            *(const uv4*)&hgel[tid][0]);
    ++ep; gbar(bar, ep);

    // ---- Phase B ----
#pragma unroll
    for (int r = 0; r < 5; ++r)
      if (actR[r])
        zvL[r * MDIM + tid] = (_Float16)vmir[((size_t)t * TKL + aR[r]) * MDIM + tid];
    __syncthreads();
#pragma unroll
    for (int k = 0; k < 2; ++k) {
      const int j = bwave + (k << 4);
      if (j < 20) {
        const int r = j >> 2;
        if (actR[r]) {
          U16 w0, w1, v0, v1;
          w0.u = *(const uv4*)(WoL + j * MDIM + (lane << 3));
          w1.u = *(const uv4*)(WoL + j * MDIM + 512 + (lane << 3));
          v0.u = *(const uv4*)(zvL + r * MDIM + (lane << 3));
          v1.u = *(const uv4*)(zvL + r * MDIM + 512 + (lane << 3));
          float acc = dot16(w0, v0, 0.f);
          acc = dot16(w1, v1, acc);
          acc = wred(acc);
          if (!lane) vOut[j] = acc;
        }
      }
    }
    {
      const int rl = bwave >> 3, kq = bwave & 7;
      U16 w2;
      w2.u = *(const uv4*)(fc2h + ((size_t)((b << 1) | rl) << 12) + (kq << 9) + (lane << 3));
#pragma unroll
      for (int c = 0; c < TKL; ++c)
        if (c < nc) {
          U16 h0;
          h0.u = *(const uv4*)(hmir + ((size_t)t * TKL + alo + c) * H4 + (kq << 9) + (lane << 3));
          float acc = dot16(w2, h0, 0.f);
          acc = wred(acc);
          if (!lane) part[rl][kq][c] = acc;
        }
    }
    __syncthreads();
    if (tid < 5 && actR[tid]) {
      float* po = ocum + aR[tid] * MDIM + rb[tid];
      fv4 o = *(const fv4*)po;
      o += *(const fv4*)&vOut[tid << 2];
      *(fv4*)po = o;
      stg16(Omir + ((size_t)(t + 1) * TKL + aR[tid]) * MDIM + rb[tid],
            __builtin_bit_cast(uv4, o));
    }
    if (bwave < nc && lane < 2) {
      float s = fc2b[(b << 1) | lane];
#pragma unroll
      for (int k = 0; k < 8; ++k) s += part[lane][k][bwave];
      sOut[bwave][lane] = s;
    }
    __syncthreads();
    if (bwave < nc && !lane) {
      const int a = alo + bwave, i = t - a;
      const float v0 = sOut[bwave][0], v1 = sOut[bwave][1];
      if (a == TKL - 1) {
        *(float2*)(S + (size_t)i * MDIM + (b << 1)) = make_float2(v0, v1);
      } else {
        uv2 sv2;
        sv2.x = __float_as_uint(v0);
        sv2.y = __float_as_uint(v1);
        stg8(Smir + ((size_t)(t + 1) * NT + i) * MDIM + (b << 1), sv2);
      }
    }
    ++ep; gbar(bar, ep);
  }
}

extern "C" void kernel_launch(void* const* d_in, const int* in_sizes, int n_in,
                              void* d_out, int out_size, void* d_ws, size_t ws_size,
                              hipStream_t stream) {
  const float* x    = (const float*)d_in[0];
  const float* W    = (const float*)d_in[1];
  const float* Wv   = (const float*)d_in[4];
  const float* Wo   = (const float*)d_in[5];
  const float* lng  = (const float*)d_in[6];
  const float* lnb  = (const float*)d_in[7];
  const float* lzg  = (const float*)d_in[8];
  const float* lzb  = (const float*)d_in[9];
  const float* fc1w = (const float*)d_in[10];
  const float* fc1b = (const float*)d_in[11];
  const float* fc2w = (const float*)d_in[12];
  const float* fc2b = (const float*)d_in[13];
  float* S = (float*)d_out;

  float* xcf  = (float*)d_ws;                 // 30720 f32
  float* ocum = xcf + 30720;                  // 10240 f32
  unsigned* bar = (unsigned*)(ocum + 10240);  // 512 u32
  float* Smir = (float*)(bar + 512);          // 40*30*1024 f32
  float* Omir = Smir + 1228800;               // 40*10*1024 f32
  float* vmir = Omir + 409600;                // 40*10*1024 f32
  _Float16* hmir = (_Float16*)(vmir + 409600);  // 40*10*4096 f16
  _Float16* Wvh  = hmir + 1638400;
  _Float16* Woh  = Wvh + 10485760;
  _Float16* fc1h = Woh + 10485760;
  _Float16* fc2h = fc1h + 4194304;

  hipLaunchKernelGGL(k_cvt, dim3(5120), dim3(256), 0, stream, Wv, Wvh, 1310720);
  hipLaunchKernelGGL(k_cvt, dim3(5120), dim3(256), 0, stream, Wo, Woh, 1310720);
  hipLaunchKernelGGL(k_cvt, dim3(2048), dim3(256), 0, stream, fc1w, fc1h, 524288);
  hipLaunchKernelGGL(k_cvt, dim3(2048), dim3(256), 0, stream, fc2w, fc2h, 524288);
  hipLaunchKernelGGL(k_xcf, dim3((NT * MDIM + 255) / 256), dim3(256), 0, stream, x, xcf);
  hipLaunchKernelGGL(k_s0, dim3(NT * MDIM / 4), dim3(256), 0, stream, xcf, W, S, Smir);
  hipMemsetAsync(ocum, 0, 10240 * sizeof(float), stream);
  hipMemsetAsync(Omir, 0, 409600 * sizeof(float), stream);
  hipMemsetAsync(bar, 0, 2048, stream);

  hipLaunchKernelGGL(k_main, dim3(GBLK), dim3(GTHR), 0, stream,
                     Wvh, Woh, fc1h, fc1b, fc2h, fc2b, lng, lnb, lzg, lzb,
                     S, ocum, Smir, Omir, vmir, hmir, bar);
}

// Round 16
// 862.056 us; speedup vs baseline: 1.9444x; 1.9444x over previous
//
#include <hip/hip_runtime.h>

#define MDIM 1024
#define H4   4096
#define TKL  10
#define NT   30
#define NWFR 39
#define GBLK 256
#define GTHR 1024
#define AGENT __HIP_MEMORY_SCOPE_AGENT

typedef _Float16 h2v __attribute__((ext_vector_type(2)));
typedef unsigned int uv4 __attribute__((ext_vector_type(4)));
typedef float fv4 __attribute__((ext_vector_type(4)));
union U16 { uv4 u; h2v h[4]; _Float16 f[8]; };

__device__ __forceinline__ float wred(float v) {
#pragma unroll
  for (int o = 32; o; o >>= 1) v += __shfl_xor(v, o, 64);
  return v;
}

__device__ __forceinline__ float dot16(const U16& w, const U16& x, float acc) {
  acc = __builtin_amdgcn_fdot2(w.h[0], x.h[0], acc, false);
  acc = __builtin_amdgcn_fdot2(w.h[1], x.h[1], acc, false);
  acc = __builtin_amdgcn_fdot2(w.h[2], x.h[2], acc, false);
  acc = __builtin_amdgcn_fdot2(w.h[3], x.h[3], acc, false);
  return acc;
}

// write-through stores (visible at coherence point, never dirty in L2)
__device__ __forceinline__ void stg16(const void* p, uv4 v) {
  asm volatile("global_store_dwordx4 %0, %1, off sc0 sc1" :: "v"(p), "v"(v) : "memory");
}

__global__ void k_cvt(const float* __restrict__ in, _Float16* __restrict__ out, int n8) {
  int g = blockIdx.x * blockDim.x + threadIdx.x;
  if (g >= n8) return;
  const float4* p = (const float4*)in;
  float4 a = p[2 * g], b = p[2 * g + 1];
  U16 o;
  o.f[0] = (_Float16)a.x; o.f[1] = (_Float16)a.y;
  o.f[2] = (_Float16)a.z; o.f[3] = (_Float16)a.w;
  o.f[4] = (_Float16)b.x; o.f[5] = (_Float16)b.y;
  o.f[6] = (_Float16)b.z; o.f[7] = (_Float16)b.w;
  ((uv4*)out)[g] = o.u;
}

__global__ void k_xcf(const float* __restrict__ x, float* __restrict__ xcf) {
  int idx = blockIdx.x * blockDim.x + threadIdx.x;
  if (idx >= NT * MDIM) return;
  int i = idx >> 10, m = idx & (MDIM - 1);
  int c = m & 31, s = m >> 5;
  const float* p = x + c * (32 * 360) + s * 360 + i * 12;
  float acc = 0.f;
#pragma unroll
  for (int k = 0; k < 12; ++k) acc += p[k];
  xcf[idx] = acc * (1.0f / 12.0f);
}

__global__ void k_s0(const float* __restrict__ xcf, const float* __restrict__ W,
                     float* __restrict__ S, float* __restrict__ Smir) {
  int wid = (blockIdx.x * blockDim.x + threadIdx.x) >> 6;
  int lane = threadIdx.x & 63;
  if (wid >= NT * MDIM) return;
  int i = wid >> 10, m = wid & (MDIM - 1);
  const float4* wr = (const float4*)(W + (size_t)m * MDIM);
  const float4* xr = (const float4*)(xcf + i * MDIM);
  float acc = 0.f;
#pragma unroll
  for (int k = 0; k < 4; ++k) {
    float4 w = wr[lane + (k << 6)];
    float4 xv = xr[lane + (k << 6)];
    acc += w.x * xv.x + w.y * xv.y + w.z * xv.z + w.w * xv.w;
  }
  acc = wred(acc);
  if (lane == 0) {
    int e = m & ~1;
    float ang = (float)i / powf(10000.0f, (float)e / 512.0f);
    float pe = (m & 1) ? cosf(ang) : sinf(ang);
    float val = acc + pe;
    S[wid] = val;
    Smir[((size_t)i * NT + i) * MDIM + m] = val;
  }
}

// two-level fence-free barrier: 8 leaves x 32 blocks + root + go flag
__device__ __forceinline__ void gbar(unsigned* bar, unsigned ep) {
  asm volatile("s_waitcnt vmcnt(0)" ::: "memory");
  __syncthreads();
  if (threadIdx.x == 0) {
    unsigned* leaf = bar + ((blockIdx.x & 7) << 5);
    const unsigned prev = __hip_atomic_fetch_add(leaf, 1u, __ATOMIC_RELAXED, AGENT);
    if (prev == ep * 32u - 1u) {
      const unsigned r = __hip_atomic_fetch_add(bar + 256, 1u, __ATOMIC_RELAXED, AGENT);
      if (r == ep * 8u - 1u)
        __hip_atomic_store(bar + 288, ep, __ATOMIC_RELAXED, AGENT);
    }
    while (__hip_atomic_load(bar + 288, __ATOMIC_RELAXED, AGENT) < ep)
      __builtin_amdgcn_s_sleep(2);
  }
  __syncthreads();
}

// 256 blocks; block b owns rows [4b,4b+4) of EVERY layer (Wv, Wo, ocum),
// fc1 rows [16b,16b+16), fc2 rows [4b,4b+4). LDS pins Wo layers 0-7, fc1, fc2.
// L2 set/XCD: Wv 2.5MB + Wo(8,9) 0.5MB + mirrors ~0.6MB < 4MB -> resident.
__global__ __launch_bounds__(GTHR) void k_main(
    const _Float16* __restrict__ Wvh, const _Float16* __restrict__ Woh,
    const _Float16* __restrict__ fc1h, const float* __restrict__ fc1b,
    const _Float16* __restrict__ fc2h, const float* __restrict__ fc2b,
    const float* __restrict__ lng, const float* __restrict__ lnb,
    const float* __restrict__ lzg, const float* __restrict__ lzb,
    float* __restrict__ S, float* __restrict__ ocum,
    float* __restrict__ Smir, float* __restrict__ Omir, float* __restrict__ vmir,
    _Float16* __restrict__ hmir, unsigned* __restrict__ bar) {
  __shared__ __align__(16) _Float16 WoL[32 * MDIM];   // 64KB: layers 0-7 x 4 rows
  __shared__ __align__(16) _Float16 fc1L[16 * MDIM];  // 32KB
  __shared__ __align__(16) _Float16 fc2L[4 * H4];     // 32KB
  __shared__ __align__(16) _Float16 zxL[10 * MDIM];   // 20KB: zL[5]|x2L[5] (A) / vL[10] (B)
  __shared__ __align__(16) float4 stats[TKL];
  __shared__ __align__(16) float vOut[40];            // [cell*4+q]
  __shared__ __align__(16) _Float16 hgel[TKL][16];
  __shared__ float part[4][4][TKL];
  __shared__ __align__(16) float sOut[TKL][4];
  _Float16* zL = zxL;                 // 5 chunk cells
  _Float16* x2L = zxL + 5 * MDIM;     // 5 chunk cells
  _Float16* vL = zxL;                 // phase B: 10 cells

  const int tid = threadIdx.x;
  const int lane = tid & 63;
  const int bwave = tid >> 6;
  const int b = blockIdx.x;
  unsigned ep = 0;

  __builtin_amdgcn_fence(__ATOMIC_ACQUIRE, "agent");

  // prologue: fc1, fc2, Wo(layers 0-7) into LDS
#pragma unroll
  for (int it = 0; it < 2; ++it) {
    const int idx = tid + (it << 10);
    ((uv4*)fc1L)[idx] = ((const uv4*)(fc1h + (size_t)b * 16384))[idx];
    ((uv4*)fc2L)[idx] = ((const uv4*)(fc2h + (size_t)b * 16384))[idx];
  }
#pragma unroll
  for (int it = 0; it < 4; ++it) {
    const int idx = tid + (it << 10);
    const int row = idx >> 7, off = idx & 127;   // 32 rows x 128 uv4
    const int layer = row >> 2, q = row & 3;
    ((uv4*)WoL)[idx] =
        *(const uv4*)(Woh + ((size_t)layer << 20) + ((size_t)((b << 2) + q) << 10) + (off << 3));
  }
  __syncthreads();

  for (int t = 0; t < NWFR; ++t) {
    const int alo = (t - (NT - 1)) > 0 ? (t - (NT - 1)) : 0;
    const int ahi = t < (TKL - 1) ? t : (TKL - 1);
    const int nc = ahi - alo + 1;
    const float* Smirt = Smir + (size_t)t * NT * MDIM;
    const float* Omirt = Omir + (size_t)t * TKL * MDIM;

    // ---- LN stats: one wave per cell ----
    if (bwave < nc) {
      const int a = alo + bwave, i = t - a;
      const fv4* sp = (const fv4*)(Smirt + (size_t)i * MDIM + (lane << 4));
      const fv4* op = (const fv4*)(Omirt + (size_t)a * MDIM + (lane << 4));
      fv4 sv[4], tv[4];
#pragma unroll
      for (int k = 0; k < 4; ++k) { sv[k] = sp[k]; tv[k] = sv[k] + op[k]; }
      float s1 = 0.f, t1 = 0.f;
#pragma unroll
      for (int k = 0; k < 4; ++k)
#pragma unroll
        for (int e = 0; e < 4; ++e) { s1 += sv[k][e]; t1 += tv[k][e]; }
      const float mu_s = wred(s1) * (1.0f / MDIM);
      const float mu_t = wred(t1) * (1.0f / MDIM);
      float s2 = 0.f, t2 = 0.f;
#pragma unroll
      for (int k = 0; k < 4; ++k)
#pragma unroll
        for (int e = 0; e < 4; ++e) {
          float d = sv[k][e] - mu_s; s2 += d * d;
          float f = tv[k][e] - mu_t; t2 += f * f;
        }
      const float var_s = wred(s2) * (1.0f / MDIM);
      const float var_t = wred(t2) * (1.0f / MDIM);
      if (!lane)
        stats[bwave] = make_float4(mu_s, rsqrtf(var_s + 1e-5f),
                                   mu_t, rsqrtf(var_t + 1e-5f));
    }
    __syncthreads();

    // ---- Phase A in 2 chunks of 5 cells: elementwise -> fc1 -> Wv ----
#pragma unroll
    for (int ch = 0; ch < 2; ++ch) {
      const int c0 = ch * 5;
      if (c0 < nc) {
        {  // elementwise: z and x2 for chunk cells
          const int cp = tid >> 7, e = (tid & 127) << 3;
          const int c = c0 + cp;
          if (cp < 5 && c < nc) {
            const int a = alo + c, i = t - a;
            const float4 st4 = stats[c];
            fv4 sA = *(const fv4*)(Smirt + (size_t)i * MDIM + e);
            fv4 sB = *(const fv4*)(Smirt + (size_t)i * MDIM + e + 4);
            fv4 oA = *(const fv4*)(Omirt + (size_t)a * MDIM + e);
            fv4 oB = *(const fv4*)(Omirt + (size_t)a * MDIM + e + 4);
            fv4 g1A = *(const fv4*)(lng + e), g1B = *(const fv4*)(lng + e + 4);
            fv4 b1A = *(const fv4*)(lnb + e), b1B = *(const fv4*)(lnb + e + 4);
            fv4 g2A = *(const fv4*)(lzg + e), g2B = *(const fv4*)(lzg + e + 4);
            fv4 b2A = *(const fv4*)(lzb + e), b2B = *(const fv4*)(lzb + e + 4);
            U16 zz, xx;
#pragma unroll
            for (int k = 0; k < 4; ++k) {
              zz.f[k] = (_Float16)((sA[k] - st4.x) * st4.y * g1A[k] + b1A[k]);
              zz.f[4 + k] = (_Float16)((sB[k] - st4.x) * st4.y * g1B[k] + b1B[k]);
              const float u0 = sA[k] + oA[k], u1 = sB[k] + oB[k];
              xx.f[k] = (_Float16)((u0 - st4.z) * st4.w * g2A[k] + b2A[k] + u0);
              xx.f[4 + k] = (_Float16)((u1 - st4.z) * st4.w * g2B[k] + b2B[k] + u1);
            }
            *(uv4*)(zL + cp * MDIM + e) = zz.u;
            *(uv4*)(x2L + cp * MDIM + e) = xx.u;
          }
        }
        __syncthreads();
        {  // fc1: wave = one of 16 rows, over chunk cells
          const int rw = bwave;
          U16 f0, f1;
          f0.u = *(const uv4*)(fc1L + rw * MDIM + (lane << 3));
          f1.u = *(const uv4*)(fc1L + rw * MDIM + 512 + (lane << 3));
          float sel = 0.f;
#pragma unroll
          for (int cc = 0; cc < 5; ++cc) {
            const int c = c0 + cc;
            if (c < nc) {
              U16 x0, x1;
              x0.u = *(const uv4*)(x2L + cc * MDIM + (lane << 3));
              x1.u = *(const uv4*)(x2L + cc * MDIM + 512 + (lane << 3));
              float acc = dot16(f0, x0, 0.f);
              acc = dot16(f1, x1, acc);
              acc = wred(acc);
              sel = (lane == cc) ? acc : sel;
            }
          }
          const float xg = sel + fc1b[(b << 4) | rw];
          const float ge = 0.5f * xg * (1.0f + erff(xg * 0.70710678118654752f));
          if (lane < 5 && c0 + lane < nc) hgel[c0 + lane][rw] = (_Float16)ge;
        }
        // Wv: 20 rows (5 chunk layers x 4), global only, consumed immediately
#pragma unroll
        for (int k = 0; k < 2; ++k) {
          const int j = bwave + (k << 4);
          if (j < 20) {
            const int rc = j >> 2, c = c0 + rc;
            if (c < nc) {
              const int layer = alo + c;
              if (t - layer != NT - 1) {
                const _Float16* wp = Wvh + ((size_t)layer << 20) +
                                     ((size_t)((b << 2) + (j & 3)) << 10);
                U16 w0, w1, z0, z1;
                w0.u = *(const uv4*)(wp + (lane << 3));
                w1.u = *(const uv4*)(wp + 512 + (lane << 3));
                z0.u = *(const uv4*)(zL + rc * MDIM + (lane << 3));
                z1.u = *(const uv4*)(zL + rc * MDIM + 512 + (lane << 3));
                float acc = dot16(w0, z0, 0.f);
                acc = dot16(w1, z1, acc);
                acc = wred(acc);
                if (!lane) vOut[(c << 2) + (j & 3)] = acc;
              }
            }
          }
        }
        __syncthreads();
      }
    }
    // mirror stores: v (16B per cell) and h (32B per cell)
    if (tid < TKL && tid < nc && (t - (alo + tid)) != NT - 1)
      stg16(vmir + ((size_t)t * TKL + alo + tid) * MDIM + (b << 2),
            __builtin_bit_cast(uv4, *(const fv4*)&vOut[tid << 2]));
    if (bwave < nc && lane < 2)
      stg16(hmir + ((size_t)t * TKL + alo + bwave) * H4 + (b << 4) + (lane << 3),
            *(const uv4*)&hgel[bwave][lane << 3]);
    ++ep; gbar(bar, ep);

    // ---- Phase B: stage v for all cells ----
#pragma unroll
    for (int c = 0; c < TKL; ++c)
      if (c < nc && (t - (alo + c)) != NT - 1)
        vL[c * MDIM + tid] = (_Float16)vmir[((size_t)t * TKL + alo + c) * MDIM + tid];
    __syncthreads();
    // Wo pass 1: LDS-resident layers (<8) ONLY — single address space per load
#pragma unroll
    for (int k = 0; k < 3; ++k) {
      const int j = bwave + (k << 4);
      if (j < 40) {
        const int c = j >> 2;
        if (c < nc) {
          const int layer = alo + c;
          if (layer < 8 && t - layer != NT - 1) {
            const _Float16* wp = WoL + ((layer << 2) + (j & 3)) * MDIM;  // LDS only
            U16 w0, w1, v0, v1;
            w0.u = *(const uv4*)(wp + (lane << 3));
            w1.u = *(const uv4*)(wp + 512 + (lane << 3));
            v0.u = *(const uv4*)(vL + c * MDIM + (lane << 3));
            v1.u = *(const uv4*)(vL + c * MDIM + 512 + (lane << 3));
            float acc = dot16(w0, v0, 0.f);
            acc = dot16(w1, v1, acc);
            acc = wred(acc);
            if (!lane) vOut[j] = acc;
          }
        }
      }
    }
    // Wo pass 2: global layers (>=8) ONLY — single address space per load
#pragma unroll
    for (int k = 0; k < 3; ++k) {
      const int j = bwave + (k << 4);
      if (j < 40) {
        const int c = j >> 2;
        if (c < nc) {
          const int layer = alo + c;
          if (layer >= 8 && t - layer != NT - 1) {
            const _Float16* wp = Woh + ((size_t)layer << 20) +
                                 ((size_t)((b << 2) + (j & 3)) << 10);  // global only
            U16 w0, w1, v0, v1;
            w0.u = *(const uv4*)(wp + (lane << 3));
            w1.u = *(const uv4*)(wp + 512 + (lane << 3));
            v0.u = *(const uv4*)(vL + c * MDIM + (lane << 3));
            v1.u = *(const uv4*)(vL + c * MDIM + 512 + (lane << 3));
            float acc = dot16(w0, v0, 0.f);
            acc = dot16(w1, v1, acc);
            acc = wred(acc);
            if (!lane) vOut[j] = acc;
          }
        }
      }
    }
    // fc2: 4 rows x 4 k-quarters (LDS weights, h broadcast from L2)
    {
      const int rl = bwave >> 2, kq = bwave & 3;
      U16 w2a, w2b;
      w2a.u = *(const uv4*)(fc2L + rl * H4 + (kq << 10) + (lane << 3));
      w2b.u = *(const uv4*)(fc2L + rl * H4 + (kq << 10) + 512 + (lane << 3));
#pragma unroll
      for (int c = 0; c < TKL; ++c)
        if (c < nc) {
          U16 h0, h1;
          const _Float16* hp = hmir + ((size_t)t * TKL + alo + c) * H4 + (kq << 10);
          h0.u = *(const uv4*)(hp + (lane << 3));
          h1.u = *(const uv4*)(hp + 512 + (lane << 3));
          float acc = dot16(w2a, h0, 0.f);
          acc = dot16(w2b, h1, acc);
          acc = wred(acc);
          if (!lane) part[rl][kq][c] = acc;
        }
    }
    __syncthreads();
    // ocum RMW (block-exclusive rows, plain cached) + Omir write-through
    if (tid < TKL && tid < nc && (t - (alo + tid)) != NT - 1) {
      const int layer = alo + tid;
      float* po = ocum + layer * MDIM + (b << 2);
      fv4 o = *(const fv4*)po;
      o += *(const fv4*)&vOut[tid << 2];
      *(fv4*)po = o;
      stg16(Omir + ((size_t)(t + 1) * TKL + layer) * MDIM + (b << 2),
            __builtin_bit_cast(uv4, o));
    }
    if (bwave < nc && lane < 4)
      sOut[bwave][lane] = part[lane][0][bwave] + part[lane][1][bwave] +
                          part[lane][2][bwave] + part[lane][3][bwave] +
                          fc2b[(b << 2) | lane];
    __syncthreads();
    if (bwave < nc && !lane) {
      const int a = alo + bwave, i = t - a;
      fv4 sv = *(const fv4*)(&sOut[bwave][0]);
      if (a == TKL - 1)
        *(fv4*)(S + (size_t)i * MDIM + (b << 2)) = sv;
      else
        stg16(Smir + ((size_t)(t + 1) * NT + i) * MDIM + (b << 2),
              __builtin_bit_cast(uv4, sv));
    }
    ++ep; gbar(bar, ep);
  }
}

extern "C" void kernel_launch(void* const* d_in, const int* in_sizes, int n_in,
                              void* d_out, int out_size, void* d_ws, size_t ws_size,
                              hipStream_t stream) {
  const float* x    = (const float*)d_in[0];
  const float* W    = (const float*)d_in[1];
  const float* Wv   = (const float*)d_in[4];
  const float* Wo   = (const float*)d_in[5];
  const float* lng  = (const float*)d_in[6];
  const float* lnb  = (const float*)d_in[7];
  const float* lzg  = (const float*)d_in[8];
  const float* lzb  = (const float*)d_in[9];
  const float* fc1w = (const float*)d_in[10];
  const float* fc1b = (const float*)d_in[11];
  const float* fc2w = (const float*)d_in[12];
  const float* fc2b = (const float*)d_in[13];
  float* S = (float*)d_out;

  float* xcf  = (float*)d_ws;                 // 30720 f32
  float* ocum = xcf + 30720;                  // 10240 f32
  unsigned* bar = (unsigned*)(ocum + 10240);  // 512 u32
  float* Smir = (float*)(bar + 512);          // 40*30*1024 f32
  float* Omir = Smir + 1228800;               // 40*10*1024 f32
  float* vmir = Omir + 409600;                // 40*10*1024 f32
  _Float16* hmir = (_Float16*)(vmir + 409600);  // 40*10*4096 f16
  _Float16* Wvh  = hmir + 1638400;
  _Float16* Woh  = Wvh + 10485760;
  _Float16* fc1h = Woh + 10485760;
  _Float16* fc2h = fc1h + 4194304;

  hipLaunchKernelGGL(k_cvt, dim3(5120), dim3(256), 0, stream, Wv, Wvh, 1310720);
  hipLaunchKernelGGL(k_cvt, dim3(5120), dim3(256), 0, stream, Wo, Woh, 1310720);
  hipLaunchKernelGGL(k_cvt, dim3(2048), dim3(256), 0, stream, fc1w, fc1h, 524288);
  hipLaunchKernelGGL(k_cvt, dim3(2048), dim3(256), 0, stream, fc2w, fc2h, 524288);
  hipLaunchKernelGGL(k_xcf, dim3((NT * MDIM + 255) / 256), dim3(256), 0, stream, x, xcf);
  hipLaunchKernelGGL(k_s0, dim3(NT * MDIM / 4), dim3(256), 0, stream, xcf, W, S, Smir);
  hipMemsetAsync(ocum, 0, 10240 * sizeof(float), stream);
  hipMemsetAsync(Omir, 0, 409600 * sizeof(float), stream);
  hipMemsetAsync(bar, 0, 2048, stream);

  hipLaunchKernelGGL(k_main, dim3(GBLK), dim3(GTHR), 0, stream,
                     Wvh, Woh, fc1h, fc1b, fc2h, fc2b, lng, lnb, lzg, lzb,
                     S, ocum, Smir, Omir, vmir, hmir, bar);
}